// Round 1
// baseline (190.029 us; speedup 1.0000x reference)
//
#include <hip/hip_runtime.h>

#define BB 512
#define HH 1024
#define CC 256
#define WW 512

__device__ __forceinline__ float wave_reduce_sum(float v) {
    #pragma unroll
    for (int off = 32; off > 0; off >>= 1) v += __shfl_xor(v, off, 64);
    return v;
}

__device__ __forceinline__ float wave_reduce_max(float v) {
    #pragma unroll
    for (int off = 32; off > 0; off >>= 1) v = fmaxf(v, __shfl_xor(v, off, 64));
    return v;
}

// One block per sample b. 256 threads = 4 waves.
// Each wave computes dot(h_p[b], psi_w[c]) for c = wave, wave+4, ...
// Then block softmax over C=256 (one thread per c).
__global__ __launch_bounds__(256) void pc_kernel(const float* __restrict__ h_p,
                                                 const float* __restrict__ psi_w,
                                                 float* __restrict__ p_c) {
    __shared__ float hp[HH];
    __shared__ float logits[CC];
    __shared__ float red[4];

    const int b = blockIdx.x;
    const int tid = threadIdx.x;
    const int wave = tid >> 6;
    const int lane = tid & 63;

    const float4* __restrict__ hp_g = (const float4*)(h_p + (size_t)b * HH);
    float4* hp_l = (float4*)hp;
    for (int i = tid; i < HH / 4; i += 256) hp_l[i] = hp_g[i];
    __syncthreads();

    for (int c = wave; c < CC; c += 4) {
        const float4* __restrict__ row = (const float4*)(psi_w + (size_t)c * HH);
        float acc = 0.f;
        #pragma unroll
        for (int k = lane; k < HH / 4; k += 64) {
            float4 a = row[k];
            float4 x = hp_l[k];
            acc = fmaf(a.x, x.x, acc);
            acc = fmaf(a.y, x.y, acc);
            acc = fmaf(a.z, x.z, acc);
            acc = fmaf(a.w, x.w, acc);
        }
        acc = wave_reduce_sum(acc);
        if (lane == 0) logits[c] = acc;
    }
    __syncthreads();

    // softmax over C: each thread owns one c
    float lv = logits[tid];
    float m = wave_reduce_max(lv);
    if (lane == 0) red[wave] = m;
    __syncthreads();
    float bm = fmaxf(fmaxf(red[0], red[1]), fmaxf(red[2], red[3]));
    float e = expf(lv - bm);
    float s = wave_reduce_sum(e);
    __syncthreads();
    if (lane == 0) red[wave] = s;
    __syncthreads();
    float bs = red[0] + red[1] + red[2] + red[3];
    p_c[(size_t)b * CC + tid] = e / bs;
}

// One block per sample b. 512 threads = 8 waves.
// Each wave computes dot(h_p[b], phi_w[c][w]) for w = wave, wave+8, ...
// Then mask + block softmax over W=512 (one thread per w).
__global__ __launch_bounds__(512) void pw_kernel(const float* __restrict__ h_p,
                                                 const int* __restrict__ tcl,
                                                 const int* __restrict__ csz,
                                                 const float* __restrict__ phi_w,
                                                 const float* __restrict__ phi_b,
                                                 float* __restrict__ p_w) {
    __shared__ float hp[HH];
    __shared__ float logits[WW];
    __shared__ float red[8];

    const int b = blockIdx.x;
    const int tid = threadIdx.x;
    const int wave = tid >> 6;
    const int lane = tid & 63;

    const int c = tcl[b];

    const float4* __restrict__ hp_g = (const float4*)(h_p + (size_t)b * HH);
    float4* hp_l = (float4*)hp;
    for (int i = tid; i < HH / 4; i += 512) hp_l[i] = hp_g[i];
    __syncthreads();

    const float* __restrict__ base = phi_w + (size_t)c * WW * HH;
    for (int w = wave; w < WW; w += 8) {
        const float4* __restrict__ row = (const float4*)(base + (size_t)w * HH);
        float acc = 0.f;
        #pragma unroll
        for (int k = lane; k < HH / 4; k += 64) {
            float4 a = row[k];
            float4 x = hp_l[k];
            acc = fmaf(a.x, x.x, acc);
            acc = fmaf(a.y, x.y, acc);
            acc = fmaf(a.z, x.z, acc);
            acc = fmaf(a.w, x.w, acc);
        }
        acc = wave_reduce_sum(acc);
        if (lane == 0) logits[w] = acc + phi_b[(size_t)c * WW + w];
    }
    __syncthreads();

    // mask + softmax over W: each thread owns one w
    const int size = csz[c];
    float lv = logits[tid];
    bool valid = tid < size;
    float mask_pos = valid ? 1.f : -1.f;
    float mask_neg = valid ? 1.f : -1e5f;
    float filt = (lv > 0.f ? lv : lv * mask_pos) * mask_neg;

    float m = wave_reduce_max(filt);
    if (lane == 0) red[wave] = m;
    __syncthreads();
    float bm = red[0];
    #pragma unroll
    for (int i = 1; i < 8; i++) bm = fmaxf(bm, red[i]);
    float e = expf(filt - bm);
    float s = wave_reduce_sum(e);
    __syncthreads();
    if (lane == 0) red[wave] = s;
    __syncthreads();
    float bs = 0.f;
    #pragma unroll
    for (int i = 0; i < 8; i++) bs += red[i];
    p_w[(size_t)b * WW + tid] = e / bs;
}

extern "C" void kernel_launch(void* const* d_in, const int* in_sizes, int n_in,
                              void* d_out, int out_size, void* d_ws, size_t ws_size,
                              hipStream_t stream) {
    const float* h_p      = (const float*)d_in[0];
    const int*   tcl      = (const int*)d_in[1];
    const int*   csz      = (const int*)d_in[2];
    const float* psi_w    = (const float*)d_in[3];
    const float* phi_w    = (const float*)d_in[4];
    const float* phi_b    = (const float*)d_in[5];

    float* p_c = (float*)d_out;                       // [B, C]
    float* p_w = (float*)d_out + (size_t)BB * CC;     // [B, W]

    pc_kernel<<<BB, 256, 0, stream>>>(h_p, psi_w, p_c);
    pw_kernel<<<BB, 512, 0, stream>>>(h_p, tcl, csz, phi_w, phi_b, p_w);
}

// Round 2
// 161.213 us; speedup vs baseline: 1.1787x; 1.1787x over previous
//
#include <hip/hip_runtime.h>

#define BB 512
#define HH 1024
#define CC 256
#define WW 512

#define SMAX 8                 // samples staged per pass in pw_logits
#define WSPLIT 4
#define WCHUNK (WW / WSPLIT)   // 128 rows per block
#define WTILE 4
#define PCS 4                  // samples per block in pc

// ---------- reductions ----------

// Full-wave (64-lane) sum via DPP — pure VALU, no LDS pipe. Result valid in lane 63.
__device__ __forceinline__ float dpp_sum64(float v) {
    union { float f; int i; } u, t;
    u.f = v;
#define DPP_ADD(ctrl) \
    t.i = __builtin_amdgcn_update_dpp(0, u.i, (ctrl), 0xf, 0xf, true); u.f += t.f;
    DPP_ADD(0x111);  // row_shr:1
    DPP_ADD(0x112);  // row_shr:2
    DPP_ADD(0x114);  // row_shr:4
    DPP_ADD(0x118);  // row_shr:8   -> lane 15 of each row-of-16 holds row sum
    DPP_ADD(0x142);  // row_bcast:15
    DPP_ADD(0x143);  // row_bcast:31 -> lane 63 holds full sum
#undef DPP_ADD
    return u.f;
}

__device__ __forceinline__ float wave_reduce_sum(float v) {
    #pragma unroll
    for (int off = 32; off > 0; off >>= 1) v += __shfl_xor(v, off, 64);
    return v;
}
__device__ __forceinline__ float wave_reduce_max(float v) {
    #pragma unroll
    for (int off = 32; off > 0; off >>= 1) v = fmaxf(v, __shfl_xor(v, off, 64));
    return v;
}

__device__ __forceinline__ float dot4_acc(float4 a, float4 x, float acc) {
    acc = fmaf(a.x, x.x, acc);
    acc = fmaf(a.y, x.y, acc);
    acc = fmaf(a.z, x.z, acc);
    acc = fmaf(a.w, x.w, acc);
    return acc;
}

// ---------- bucket samples by cluster ----------
// One block, 512 threads. lists[c*BB + slot] = b. Slot order is atomic-race
// dependent but per-sample results are independent of slot -> deterministic output.
__global__ __launch_bounds__(512) void bucket_kernel(const int* __restrict__ tcl,
                                                     int* __restrict__ counts,
                                                     int* __restrict__ lists) {
    __shared__ int cnt[CC];
    const int t = threadIdx.x;
    if (t < CC) cnt[t] = 0;
    __syncthreads();
    const int c = tcl[t];
    const int slot = atomicAdd(&cnt[c], 1);
    lists[c * BB + slot] = t;
    __syncthreads();
    if (t < CC) counts[t] = cnt[t];
}

// ---------- p_c: 4 samples per block, stream psi_w once per block ----------
__global__ __launch_bounds__(256) void pc_kernel(const float* __restrict__ h_p,
                                                 const float* __restrict__ psi_w,
                                                 float* __restrict__ p_c) {
    __shared__ float hp[PCS][HH];   // 16 KB
    __shared__ float lg[PCS][CC];   // 4 KB
    __shared__ float red[4];

    const int b0 = blockIdx.x * PCS;
    const int tid = threadIdx.x;
    const int wave = tid >> 6;
    const int lane = tid & 63;

    for (int i = tid; i < PCS * (HH / 4); i += 256) {
        const int s = i >> 8;          // / 256
        const int k = i & 255;
        ((float4*)hp[s])[k] = ((const float4*)(h_p + (size_t)(b0 + s) * HH))[k];
    }
    __syncthreads();

    // each wave owns 64 contiguous c's, tiled by 4
    for (int cg = 0; cg < 64 / WTILE; cg++) {
        const int c0 = wave * 64 + cg * WTILE;
        float acc[WTILE][PCS];
        #pragma unroll
        for (int a = 0; a < WTILE; a++)
            #pragma unroll
            for (int s = 0; s < PCS; s++) acc[a][s] = 0.f;

        #pragma unroll
        for (int i = 0; i < (HH / 4) / 64; i++) {
            const int k = lane + i * 64;
            float4 r0 = ((const float4*)(psi_w + (size_t)(c0 + 0) * HH))[k];
            float4 r1 = ((const float4*)(psi_w + (size_t)(c0 + 1) * HH))[k];
            float4 r2 = ((const float4*)(psi_w + (size_t)(c0 + 2) * HH))[k];
            float4 r3 = ((const float4*)(psi_w + (size_t)(c0 + 3) * HH))[k];
            #pragma unroll
            for (int s = 0; s < PCS; s++) {
                float4 x = ((const float4*)hp[s])[k];
                acc[0][s] = dot4_acc(r0, x, acc[0][s]);
                acc[1][s] = dot4_acc(r1, x, acc[1][s]);
                acc[2][s] = dot4_acc(r2, x, acc[2][s]);
                acc[3][s] = dot4_acc(r3, x, acc[3][s]);
            }
        }
        #pragma unroll
        for (int a = 0; a < WTILE; a++)
            #pragma unroll
            for (int s = 0; s < PCS; s++) {
                float v = dpp_sum64(acc[a][s]);
                if (lane == 63) lg[s][c0 + a] = v;
            }
    }
    __syncthreads();

    // softmax per sample over C=256 (one thread per c)
    for (int s = 0; s < PCS; s++) {
        const float lv = lg[s][tid];
        float m = wave_reduce_max(lv);
        if (lane == 0) red[wave] = m;
        __syncthreads();
        const float bm = fmaxf(fmaxf(red[0], red[1]), fmaxf(red[2], red[3]));
        const float e = expf(lv - bm);
        float sm = wave_reduce_sum(e);
        __syncthreads();
        if (lane == 0) red[wave] = sm;
        __syncthreads();
        const float bs = red[0] + red[1] + red[2] + red[3];
        p_c[(size_t)(b0 + s) * CC + tid] = e / bs;
        __syncthreads();
    }
}

// ---------- p_w logits: one block per (cluster, W-chunk), phi_w read once ----------
__global__ __launch_bounds__(256) void pw_logits_kernel(const float* __restrict__ h_p,
                                                        const int* __restrict__ counts,
                                                        const int* __restrict__ lists,
                                                        const float* __restrict__ phi_w,
                                                        const float* __restrict__ phi_b,
                                                        float* __restrict__ logits_ws) {
    const int c = blockIdx.x;
    const int n = counts[c];
    if (n == 0) return;
    const int split = blockIdx.y;

    __shared__ float hp[SMAX][HH];   // 32 KB
    __shared__ int sid[SMAX];

    const int tid = threadIdx.x;
    const int wave = tid >> 6;
    const int lane = tid & 63;

    const int wbase = split * WCHUNK + wave * (WCHUNK / 4);   // 32 rows per wave
    const float* __restrict__ base = phi_w + (size_t)c * WW * HH;

    for (int s0 = 0; s0 < n; s0 += SMAX) {
        __syncthreads();   // protect previous pass's hp use
        if (tid < SMAX) sid[tid] = (s0 + tid < n) ? lists[c * BB + s0 + tid] : -1;
        __syncthreads();
        for (int i = tid; i < SMAX * (HH / 4); i += 256) {
            const int s = i >> 8;      // / 256
            const int k = i & 255;
            const int b = sid[s];
            float4 v = make_float4(0.f, 0.f, 0.f, 0.f);
            if (b >= 0) v = ((const float4*)(h_p + (size_t)b * HH))[k];
            ((float4*)hp[s])[k] = v;
        }
        __syncthreads();

        for (int wg = 0; wg < (WCHUNK / 4) / WTILE; wg++) {   // 8 groups of 4 rows
            const int w0 = wbase + wg * WTILE;
            float acc[WTILE][SMAX];
            #pragma unroll
            for (int a = 0; a < WTILE; a++)
                #pragma unroll
                for (int s = 0; s < SMAX; s++) acc[a][s] = 0.f;

            #pragma unroll
            for (int i = 0; i < (HH / 4) / 64; i++) {
                const int k = lane + i * 64;
                float4 r0 = ((const float4*)(base + (size_t)(w0 + 0) * HH))[k];
                float4 r1 = ((const float4*)(base + (size_t)(w0 + 1) * HH))[k];
                float4 r2 = ((const float4*)(base + (size_t)(w0 + 2) * HH))[k];
                float4 r3 = ((const float4*)(base + (size_t)(w0 + 3) * HH))[k];
                #pragma unroll
                for (int s = 0; s < SMAX; s++) {
                    float4 x = ((const float4*)hp[s])[k];
                    acc[0][s] = dot4_acc(r0, x, acc[0][s]);
                    acc[1][s] = dot4_acc(r1, x, acc[1][s]);
                    acc[2][s] = dot4_acc(r2, x, acc[2][s]);
                    acc[3][s] = dot4_acc(r3, x, acc[3][s]);
                }
            }

            #pragma unroll
            for (int a = 0; a < WTILE; a++) {
                const float bias = phi_b[(size_t)c * WW + (w0 + a)];
                #pragma unroll
                for (int s = 0; s < SMAX; s++) {
                    float v = dpp_sum64(acc[a][s]);
                    if (lane == 63 && sid[s] >= 0) {
                        logits_ws[(size_t)sid[s] * WW + (w0 + a)] = v + bias;
                    }
                }
            }
        }
    }
}

// ---------- p_w: mask + softmax over W ----------
__global__ __launch_bounds__(512) void pw_softmax_kernel(const int* __restrict__ tcl,
                                                         const int* __restrict__ csz,
                                                         const float* __restrict__ logits_ws,
                                                         float* __restrict__ p_w) {
    __shared__ float red[8];
    const int b = blockIdx.x;
    const int tid = threadIdx.x;
    const int wave = tid >> 6;
    const int lane = tid & 63;

    const int c = tcl[b];
    const int size = csz[c];

    const float lv = logits_ws[(size_t)b * WW + tid];
    const bool valid = tid < size;
    const float mask_pos = valid ? 1.f : -1.f;
    const float mask_neg = valid ? 1.f : -1e5f;
    const float filt = (lv > 0.f ? lv : lv * mask_pos) * mask_neg;

    float m = wave_reduce_max(filt);
    if (lane == 0) red[wave] = m;
    __syncthreads();
    float bm = red[0];
    #pragma unroll
    for (int i = 1; i < 8; i++) bm = fmaxf(bm, red[i]);
    const float e = expf(filt - bm);
    float s = wave_reduce_sum(e);
    __syncthreads();
    if (lane == 0) red[wave] = s;
    __syncthreads();
    float bs = 0.f;
    #pragma unroll
    for (int i = 0; i < 8; i++) bs += red[i];
    p_w[(size_t)b * WW + tid] = e / bs;
}

extern "C" void kernel_launch(void* const* d_in, const int* in_sizes, int n_in,
                              void* d_out, int out_size, void* d_ws, size_t ws_size,
                              hipStream_t stream) {
    const float* h_p   = (const float*)d_in[0];
    const int*   tcl   = (const int*)d_in[1];
    const int*   csz   = (const int*)d_in[2];
    const float* psi_w = (const float*)d_in[3];
    const float* phi_w = (const float*)d_in[4];
    const float* phi_b = (const float*)d_in[5];

    float* p_c = (float*)d_out;                    // [B, C]
    float* p_w = (float*)d_out + (size_t)BB * CC;  // [B, W]

    // workspace layout
    int*   counts    = (int*)d_ws;                                  // CC ints (1 KB)
    int*   lists     = (int*)d_ws + CC;                             // CC*BB ints (512 KB)
    float* logits_ws = (float*)((char*)d_ws + (size_t)(CC + CC * BB) * 4);  // BB*WW floats (1 MB)

    bucket_kernel<<<1, 512, 0, stream>>>(tcl, counts, lists);
    pc_kernel<<<BB / PCS, 256, 0, stream>>>(h_p, psi_w, p_c);
    pw_logits_kernel<<<dim3(CC, WSPLIT), 256, 0, stream>>>(h_p, counts, lists, phi_w, phi_b, logits_ws);
    pw_softmax_kernel<<<BB, 512, 0, stream>>>(tcl, csz, logits_ws, p_w);
}

// Round 3
// 148.916 us; speedup vs baseline: 1.2761x; 1.0826x over previous
//
#include <hip/hip_runtime.h>

#define BB 512
#define HH 1024
#define CC 256
#define WW 512

#define SMAX 8                 // samples staged per pass in pw_logits
#define WSPLIT 4
#define WCHUNK (WW / WSPLIT)   // 128 rows per block
#define PCS 4                  // samples per block in pc
#define WTILE 4

// ---------- reductions ----------

// Full-wave (64-lane) sum via DPP — pure VALU, no LDS pipe. Result valid in lane 63.
__device__ __forceinline__ float dpp_sum64(float v) {
    union { float f; int i; } u, t;
    u.f = v;
#define DPP_ADD(ctrl) \
    t.i = __builtin_amdgcn_update_dpp(0, u.i, (ctrl), 0xf, 0xf, true); u.f += t.f;
    DPP_ADD(0x111);  // row_shr:1
    DPP_ADD(0x112);  // row_shr:2
    DPP_ADD(0x114);  // row_shr:4
    DPP_ADD(0x118);  // row_shr:8   -> lane 15 of each row-of-16 holds row sum
    DPP_ADD(0x142);  // row_bcast:15
    DPP_ADD(0x143);  // row_bcast:31 -> lane 63 holds full sum
#undef DPP_ADD
    return u.f;
}

__device__ __forceinline__ float wave_reduce_sum(float v) {
    #pragma unroll
    for (int off = 32; off > 0; off >>= 1) v += __shfl_xor(v, off, 64);
    return v;
}
__device__ __forceinline__ float wave_reduce_max(float v) {
    #pragma unroll
    for (int off = 32; off > 0; off >>= 1) v = fmaxf(v, __shfl_xor(v, off, 64));
    return v;
}

__device__ __forceinline__ float dot4_acc(float4 a, float4 x, float acc) {
    acc = fmaf(a.x, x.x, acc);
    acc = fmaf(a.y, x.y, acc);
    acc = fmaf(a.z, x.z, acc);
    acc = fmaf(a.w, x.w, acc);
    return acc;
}

// ---------- bucket samples by cluster ----------
__global__ __launch_bounds__(512) void bucket_kernel(const int* __restrict__ tcl,
                                                     int* __restrict__ counts,
                                                     int* __restrict__ lists) {
    __shared__ int cnt[CC];
    const int t = threadIdx.x;
    if (t < CC) cnt[t] = 0;
    __syncthreads();
    const int c = tcl[t];
    const int slot = atomicAdd(&cnt[c], 1);
    lists[c * BB + slot] = t;
    __syncthreads();
    if (t < CC) counts[t] = cnt[t];
}

// ---------- p_c: 4 samples per block, stream psi_w once per block ----------
__global__ __launch_bounds__(256) void pc_kernel(const float* __restrict__ h_p,
                                                 const float* __restrict__ psi_w,
                                                 float* __restrict__ p_c) {
    __shared__ float hp[PCS][HH];   // 16 KB
    __shared__ float lg[PCS][CC];   // 4 KB
    __shared__ float red[4];

    const int b0 = blockIdx.x * PCS;
    const int tid = threadIdx.x;
    const int wave = tid >> 6;
    const int lane = tid & 63;

    for (int i = tid; i < PCS * (HH / 4); i += 256) {
        const int s = i >> 8;
        const int k = i & 255;
        ((float4*)hp[s])[k] = ((const float4*)(h_p + (size_t)(b0 + s) * HH))[k];
    }
    __syncthreads();

    for (int cg = 0; cg < 64 / WTILE; cg++) {
        const int c0 = wave * 64 + cg * WTILE;
        float acc[WTILE][PCS];
        #pragma unroll
        for (int a = 0; a < WTILE; a++)
            #pragma unroll
            for (int s = 0; s < PCS; s++) acc[a][s] = 0.f;

        #pragma unroll
        for (int i = 0; i < (HH / 4) / 64; i++) {
            const int k = lane + i * 64;
            float4 r0 = ((const float4*)(psi_w + (size_t)(c0 + 0) * HH))[k];
            float4 r1 = ((const float4*)(psi_w + (size_t)(c0 + 1) * HH))[k];
            float4 r2 = ((const float4*)(psi_w + (size_t)(c0 + 2) * HH))[k];
            float4 r3 = ((const float4*)(psi_w + (size_t)(c0 + 3) * HH))[k];
            #pragma unroll
            for (int s = 0; s < PCS; s++) {
                float4 x = ((const float4*)hp[s])[k];
                acc[0][s] = dot4_acc(r0, x, acc[0][s]);
                acc[1][s] = dot4_acc(r1, x, acc[1][s]);
                acc[2][s] = dot4_acc(r2, x, acc[2][s]);
                acc[3][s] = dot4_acc(r3, x, acc[3][s]);
            }
        }
        #pragma unroll
        for (int a = 0; a < WTILE; a++)
            #pragma unroll
            for (int s = 0; s < PCS; s++) {
                float v = dpp_sum64(acc[a][s]);
                if (lane == 63) lg[s][c0 + a] = v;
            }
    }
    __syncthreads();

    for (int s = 0; s < PCS; s++) {
        const float lv = lg[s][tid];
        float m = wave_reduce_max(lv);
        if (lane == 0) red[wave] = m;
        __syncthreads();
        const float bm = fmaxf(fmaxf(red[0], red[1]), fmaxf(red[2], red[3]));
        const float e = expf(lv - bm);
        float sm = wave_reduce_sum(e);
        __syncthreads();
        if (lane == 0) red[wave] = sm;
        __syncthreads();
        const float bs = red[0] + red[1] + red[2] + red[3];
        p_c[(size_t)(b0 + s) * CC + tid] = e / bs;
        __syncthreads();
    }
}

// ---------- p_w logits: one block per (cluster, W-chunk) ----------
// 512 threads = 8 waves. Each wave streams one 4 KB phi_w row at a time
// (contiguous float4 loads), double-buffering the next row in registers so
// 8 KB/wave stays in flight. Runtime ns-loop: no wasted FLOPs when n < SMAX.
__global__ __launch_bounds__(512) void pw_logits_kernel(const float* __restrict__ h_p,
                                                        const int* __restrict__ counts,
                                                        const int* __restrict__ lists,
                                                        const float* __restrict__ phi_w,
                                                        const float* __restrict__ phi_b,
                                                        float* __restrict__ logits_ws) {
    const int c = blockIdx.x;
    const int n = counts[c];
    if (n == 0) return;
    const int split = blockIdx.y;

    __shared__ float hp[SMAX][HH];   // 32 KB
    __shared__ int sid[SMAX];

    const int tid = threadIdx.x;
    const int wave = tid >> 6;
    const int lane = tid & 63;

    const float* __restrict__ base = phi_w + (size_t)c * WW * HH;
    const int wbase = split * WCHUNK + wave;   // rows wbase, wbase+8, ... (16 rows)

    for (int s0 = 0; s0 < n; s0 += SMAX) {
        const int ns = min(SMAX, n - s0);
        __syncthreads();   // protect previous pass's hp/sid
        if (tid < ns) sid[tid] = lists[c * BB + s0 + tid];
        __syncthreads();
        for (int i = tid; i < ns * (HH / 4); i += 512) {
            const int s = i >> 8;
            const int k = i & 255;
            ((float4*)hp[s])[k] = ((const float4*)(h_p + (size_t)sid[s] * HH))[k];
        }
        __syncthreads();

        // prime first row
        const float4* rp = (const float4*)(base + (size_t)wbase * HH);
        float4 a0 = rp[lane];
        float4 a1 = rp[lane + 64];
        float4 a2 = rp[lane + 128];
        float4 a3 = rp[lane + 192];

        for (int r = 0; r < WCHUNK / 8; r++) {
            const int w = wbase + r * 8;
            // issue next row's loads before consuming current row
            const int wn = (r < WCHUNK / 8 - 1) ? (w + 8) : w;
            const float4* np = (const float4*)(base + (size_t)wn * HH);
            float4 b0 = np[lane];
            float4 b1 = np[lane + 64];
            float4 b2 = np[lane + 128];
            float4 b3 = np[lane + 192];

            const float bias = phi_b[(size_t)c * WW + w];

            for (int s = 0; s < ns; s++) {
                const float4* __restrict__ xs = (const float4*)hp[s];
                float acc = 0.f;
                acc = dot4_acc(a0, xs[lane], acc);
                acc = dot4_acc(a1, xs[lane + 64], acc);
                acc = dot4_acc(a2, xs[lane + 128], acc);
                acc = dot4_acc(a3, xs[lane + 192], acc);
                const float v = dpp_sum64(acc);
                if (lane == 63) {
                    logits_ws[(size_t)sid[s] * WW + w] = v + bias;
                }
            }
            a0 = b0; a1 = b1; a2 = b2; a3 = b3;
        }
    }
}

// ---------- p_w: mask + softmax over W ----------
__global__ __launch_bounds__(512) void pw_softmax_kernel(const int* __restrict__ tcl,
                                                         const int* __restrict__ csz,
                                                         const float* __restrict__ logits_ws,
                                                         float* __restrict__ p_w) {
    __shared__ float red[8];
    const int b = blockIdx.x;
    const int tid = threadIdx.x;
    const int wave = tid >> 6;
    const int lane = tid & 63;

    const int c = tcl[b];
    const int size = csz[c];

    const float lv = logits_ws[(size_t)b * WW + tid];
    const bool valid = tid < size;
    const float mask_pos = valid ? 1.f : -1.f;
    const float mask_neg = valid ? 1.f : -1e5f;
    const float filt = (lv > 0.f ? lv : lv * mask_pos) * mask_neg;

    float m = wave_reduce_max(filt);
    if (lane == 0) red[wave] = m;
    __syncthreads();
    float bm = red[0];
    #pragma unroll
    for (int i = 1; i < 8; i++) bm = fmaxf(bm, red[i]);
    const float e = expf(filt - bm);
    float s = wave_reduce_sum(e);
    __syncthreads();
    if (lane == 0) red[wave] = s;
    __syncthreads();
    float bs = 0.f;
    #pragma unroll
    for (int i = 0; i < 8; i++) bs += red[i];
    p_w[(size_t)b * WW + tid] = e / bs;
}

extern "C" void kernel_launch(void* const* d_in, const int* in_sizes, int n_in,
                              void* d_out, int out_size, void* d_ws, size_t ws_size,
                              hipStream_t stream) {
    const float* h_p   = (const float*)d_in[0];
    const int*   tcl   = (const int*)d_in[1];
    const int*   csz   = (const int*)d_in[2];
    const float* psi_w = (const float*)d_in[3];
    const float* phi_w = (const float*)d_in[4];
    const float* phi_b = (const float*)d_in[5];

    float* p_c = (float*)d_out;                    // [B, C]
    float* p_w = (float*)d_out + (size_t)BB * CC;  // [B, W]

    int*   counts    = (int*)d_ws;                                  // CC ints
    int*   lists     = (int*)d_ws + CC;                             // CC*BB ints
    float* logits_ws = (float*)((char*)d_ws + (size_t)(CC + CC * BB) * 4);  // BB*WW floats

    bucket_kernel<<<1, 512, 0, stream>>>(tcl, counts, lists);
    pc_kernel<<<BB / PCS, 256, 0, stream>>>(h_p, psi_w, p_c);
    pw_logits_kernel<<<dim3(CC, WSPLIT), 512, 0, stream>>>(h_p, counts, lists, phi_w, phi_b, logits_ws);
    pw_softmax_kernel<<<BB, 512, 0, stream>>>(tcl, csz, logits_ws, p_w);
}

// Round 4
// 120.309 us; speedup vs baseline: 1.5795x; 1.2378x over previous
//
#include <hip/hip_runtime.h>

#define BB 512
#define HH 1024
#define CC 256
#define WW 512

#define SMAX 8                 // samples staged per pass in pw path
#define WSPLIT 8
#define WCHUNK (WW / WSPLIT)   // 64 rows per pw block
#define PCS 4                  // samples per block in pc path
#define NPC (BB / PCS)         // 128 pc blocks
#define NPW (CC * WSPLIT)      // 2048 pw blocks
#define WTILE 4

typedef float f4 __attribute__((ext_vector_type(4)));

__device__ __forceinline__ f4 ntload(const f4* p) {
    return __builtin_nontemporal_load(p);
}

// ---------- reductions ----------

// Full-wave (64-lane) sum via DPP — pure VALU. Result valid in lane 63.
__device__ __forceinline__ float dpp_sum64(float v) {
    union { float f; int i; } u, t;
    u.f = v;
#define DPP_ADD(ctrl) \
    t.i = __builtin_amdgcn_update_dpp(0, u.i, (ctrl), 0xf, 0xf, true); u.f += t.f;
    DPP_ADD(0x111);  // row_shr:1
    DPP_ADD(0x112);  // row_shr:2
    DPP_ADD(0x114);  // row_shr:4
    DPP_ADD(0x118);  // row_shr:8
    DPP_ADD(0x142);  // row_bcast:15
    DPP_ADD(0x143);  // row_bcast:31
#undef DPP_ADD
    return u.f;
}

__device__ __forceinline__ float wave_reduce_sum(float v) {
    #pragma unroll
    for (int off = 32; off > 0; off >>= 1) v += __shfl_xor(v, off, 64);
    return v;
}
__device__ __forceinline__ float wave_reduce_max(float v) {
    #pragma unroll
    for (int off = 32; off > 0; off >>= 1) v = fmaxf(v, __shfl_xor(v, off, 64));
    return v;
}

__device__ __forceinline__ float dot4_acc(f4 a, f4 x, float acc) {
    acc = fmaf(a.x, x.x, acc);
    acc = fmaf(a.y, x.y, acc);
    acc = fmaf(a.z, x.z, acc);
    acc = fmaf(a.w, x.w, acc);
    return acc;
}

// Shared-memory budget: pw path needs SMAX*HH floats (32 KB) + BB ints (2 KB) + 1 int.
// pc path needs PCS*HH (16 KB) + PCS*CC (4 KB) + 4 floats. Union via raw buffer.
#define SMEM_BYTES (SMAX * HH * 4 + BB * 4 + 64)

// ---------- fused kernel: blocks [0,NPC) do p_c; blocks [NPC, NPC+NPW) do pw logits ----------
__global__ __launch_bounds__(256) void fused_kernel(const float* __restrict__ h_p,
                                                    const int* __restrict__ tcl,
                                                    const float* __restrict__ psi_w,
                                                    const float* __restrict__ phi_w,
                                                    const float* __restrict__ phi_b,
                                                    float* __restrict__ p_c,
                                                    float* __restrict__ logits_ws) {
    __shared__ __align__(16) char smem[SMEM_BYTES];

    const int bid = blockIdx.x;
    const int tid = threadIdx.x;
    const int wave = tid >> 6;
    const int lane = tid & 63;

    if (bid < NPC) {
        // ================= p_c path =================
        float* hp = (float*)smem;                         // [PCS][HH]
        float* lg = hp + PCS * HH;                        // [PCS][CC]
        float* red = lg + PCS * CC;                       // [4]

        const int b0 = bid * PCS;

        for (int i = tid; i < PCS * (HH / 4); i += 256) {
            const int s = i >> 8;
            const int k = i & 255;
            ((f4*)(hp + s * HH))[k] = ((const f4*)(h_p + (size_t)(b0 + s) * HH))[k];
        }
        __syncthreads();

        for (int cg = 0; cg < 64 / WTILE; cg++) {
            const int c0 = wave * 64 + cg * WTILE;
            float acc[WTILE][PCS];
            #pragma unroll
            for (int a = 0; a < WTILE; a++)
                #pragma unroll
                for (int s = 0; s < PCS; s++) acc[a][s] = 0.f;

            #pragma unroll
            for (int i = 0; i < (HH / 4) / 64; i++) {
                const int k = lane + i * 64;
                f4 r0 = ((const f4*)(psi_w + (size_t)(c0 + 0) * HH))[k];
                f4 r1 = ((const f4*)(psi_w + (size_t)(c0 + 1) * HH))[k];
                f4 r2 = ((const f4*)(psi_w + (size_t)(c0 + 2) * HH))[k];
                f4 r3 = ((const f4*)(psi_w + (size_t)(c0 + 3) * HH))[k];
                #pragma unroll
                for (int s = 0; s < PCS; s++) {
                    f4 x = ((const f4*)(hp + s * HH))[k];
                    acc[0][s] = dot4_acc(r0, x, acc[0][s]);
                    acc[1][s] = dot4_acc(r1, x, acc[1][s]);
                    acc[2][s] = dot4_acc(r2, x, acc[2][s]);
                    acc[3][s] = dot4_acc(r3, x, acc[3][s]);
                }
            }
            #pragma unroll
            for (int a = 0; a < WTILE; a++)
                #pragma unroll
                for (int s = 0; s < PCS; s++) {
                    float v = dpp_sum64(acc[a][s]);
                    if (lane == 63) lg[s * CC + c0 + a] = v;
                }
        }
        __syncthreads();

        for (int s = 0; s < PCS; s++) {
            const float lv = lg[s * CC + tid];
            float m = wave_reduce_max(lv);
            if (lane == 0) red[wave] = m;
            __syncthreads();
            const float bm = fmaxf(fmaxf(red[0], red[1]), fmaxf(red[2], red[3]));
            const float e = expf(lv - bm);
            float sm = wave_reduce_sum(e);
            __syncthreads();
            if (lane == 0) red[wave] = sm;
            __syncthreads();
            const float bs = red[0] + red[1] + red[2] + red[3];
            p_c[(size_t)(b0 + s) * CC + tid] = e / bs;
            __syncthreads();
        }
        return;
    }

    // ================= pw logits path =================
    const int pwid = bid - NPC;
    const int c = pwid >> 3;          // / WSPLIT
    const int split = pwid & (WSPLIT - 1);

    float* hp = (float*)smem;                         // [SMAX][HH]
    int* list = (int*)(smem + SMAX * HH * 4);         // [BB]
    int* cnt = list + BB;

    // per-block bucketing: scan tcl for samples routed to cluster c.
    // Slot order is atomic-race dependent, but per-sample results are
    // slot-independent -> deterministic output.
    if (tid == 0) *cnt = 0;
    __syncthreads();
    for (int t = tid; t < BB; t += 256) {
        if (tcl[t] == c) {
            int s = atomicAdd(cnt, 1);
            list[s] = t;
        }
    }
    __syncthreads();
    const int n = *cnt;
    if (n == 0) return;

    const float* __restrict__ base = phi_w + (size_t)c * WW * HH;
    const int wbase = split * WCHUNK + wave;          // rows wbase, wbase+4, ... (16 rows)

    for (int s0 = 0; s0 < n; s0 += SMAX) {
        const int ns = min(SMAX, n - s0);
        __syncthreads();   // protect previous pass's hp
        for (int i = tid; i < ns * (HH / 4); i += 256) {
            const int s = i >> 8;
            const int k = i & 255;
            ((f4*)(hp + s * HH))[k] = ((const f4*)(h_p + (size_t)list[s0 + s] * HH))[k];
        }
        __syncthreads();

        // prime first row (non-temporal: phi_w lines are read exactly once)
        const f4* rp = (const f4*)(base + (size_t)wbase * HH);
        f4 a0 = ntload(rp + lane);
        f4 a1 = ntload(rp + lane + 64);
        f4 a2 = ntload(rp + lane + 128);
        f4 a3 = ntload(rp + lane + 192);

        for (int r = 0; r < WCHUNK / 4; r++) {
            const int w = wbase + r * 4;
            const int wn = (r < WCHUNK / 4 - 1) ? (w + 4) : w;
            const f4* np = (const f4*)(base + (size_t)wn * HH);
            f4 b0 = ntload(np + lane);
            f4 b1 = ntload(np + lane + 64);
            f4 b2 = ntload(np + lane + 128);
            f4 b3 = ntload(np + lane + 192);

            const float bias = phi_b[(size_t)c * WW + w];

            for (int s = 0; s < ns; s++) {
                const f4* __restrict__ xs = (const f4*)(hp + s * HH);
                float acc = 0.f;
                acc = dot4_acc(a0, xs[lane], acc);
                acc = dot4_acc(a1, xs[lane + 64], acc);
                acc = dot4_acc(a2, xs[lane + 128], acc);
                acc = dot4_acc(a3, xs[lane + 192], acc);
                const float v = dpp_sum64(acc);
                if (lane == 63) {
                    logits_ws[(size_t)list[s0 + s] * WW + w] = v + bias;
                }
            }
            a0 = b0; a1 = b1; a2 = b2; a3 = b3;
        }
    }
}

// ---------- p_w: mask + softmax over W ----------
__global__ __launch_bounds__(512) void pw_softmax_kernel(const int* __restrict__ tcl,
                                                         const int* __restrict__ csz,
                                                         const float* __restrict__ logits_ws,
                                                         float* __restrict__ p_w) {
    __shared__ float red[8];
    const int b = blockIdx.x;
    const int tid = threadIdx.x;
    const int wave = tid >> 6;
    const int lane = tid & 63;

    const int c = tcl[b];
    const int size = csz[c];

    const float lv = logits_ws[(size_t)b * WW + tid];
    const bool valid = tid < size;
    const float mask_pos = valid ? 1.f : -1.f;
    const float mask_neg = valid ? 1.f : -1e5f;
    const float filt = (lv > 0.f ? lv : lv * mask_pos) * mask_neg;

    float m = wave_reduce_max(filt);
    if (lane == 0) red[wave] = m;
    __syncthreads();
    float bm = red[0];
    #pragma unroll
    for (int i = 1; i < 8; i++) bm = fmaxf(bm, red[i]);
    const float e = expf(filt - bm);
    float s = wave_reduce_sum(e);
    __syncthreads();
    if (lane == 0) red[wave] = s;
    __syncthreads();
    float bs = 0.f;
    #pragma unroll
    for (int i = 0; i < 8; i++) bs += red[i];
    p_w[(size_t)b * WW + tid] = e / bs;
}

extern "C" void kernel_launch(void* const* d_in, const int* in_sizes, int n_in,
                              void* d_out, int out_size, void* d_ws, size_t ws_size,
                              hipStream_t stream) {
    const float* h_p   = (const float*)d_in[0];
    const int*   tcl   = (const int*)d_in[1];
    const int*   csz   = (const int*)d_in[2];
    const float* psi_w = (const float*)d_in[3];
    const float* phi_w = (const float*)d_in[4];
    const float* phi_b = (const float*)d_in[5];

    float* p_c = (float*)d_out;                    // [B, C]
    float* p_w = (float*)d_out + (size_t)BB * CC;  // [B, W]

    float* logits_ws = (float*)d_ws;               // BB*WW floats (1 MB)

    fused_kernel<<<NPC + NPW, 256, 0, stream>>>(h_p, tcl, psi_w, phi_w, phi_b, p_c, logits_ws);
    pw_softmax_kernel<<<BB, 512, 0, stream>>>(tcl, csz, logits_ws, p_w);
}